// Round 1
// baseline (1094.304 us; speedup 1.0000x reference)
//
#include <hip/hip_runtime.h>
#include <hip/hip_bf16.h>
#include <math.h>

// ---------------------------------------------------------------------------
// 3-layer GCN: per layer  h' = Dis (A+I) Dis (h W) + b   (Dis = D^{-1/2})
// Pipeline: count deg -> scan (col_ptr, cursor, dis) -> fill CSR(by dst)
//           gemm -> aggregate(+bias,+relu) x3 -> log_softmax
// ---------------------------------------------------------------------------

__global__ void k_count(const int* __restrict__ col, int E, int* __restrict__ cnt) {
    int i = blockIdx.x * blockDim.x + threadIdx.x;
    if (i < E) atomicAdd(&cnt[col[i]], 1);
}

__global__ __launch_bounds__(1024) void k_scan(const int* __restrict__ cnt,
                                               int* __restrict__ ptr,
                                               int* __restrict__ cur,
                                               float* __restrict__ dis, int N) {
    __shared__ int sm[1024];
    int t = threadIdx.x;
    int chunk = (N + 1023) >> 10;
    int lo = t * chunk;
    int hi = min(lo + chunk, N);
    int s = 0;
    for (int i = lo; i < hi; ++i) s += cnt[i];
    sm[t] = s;
    __syncthreads();
    for (int off = 1; off < 1024; off <<= 1) {
        int v = (t >= off) ? sm[t - off] : 0;
        __syncthreads();
        sm[t] += v;
        __syncthreads();
    }
    int run = sm[t] - s;  // exclusive prefix of this thread's chunk
    for (int i = lo; i < hi; ++i) {
        ptr[i] = run;
        cur[i] = run;
        int d = cnt[i];
        dis[i] = rsqrtf((float)(d + 1));  // +1 self-loop; deg>=1
        run += d;
    }
}

__global__ void k_fill(const int* __restrict__ row, const int* __restrict__ col,
                       int E, int* __restrict__ cur, int* __restrict__ esrc) {
    int i = blockIdx.x * blockDim.x + threadIdx.x;
    if (i < E) {
        int p = atomicAdd(&cur[col[i]], 1);
        esrc[p] = row[i];
    }
}

// ---- GEMM: Y[M][128] = X[M][128] @ W[128][128], no bias (added post-agg) ----
// block 256 = 16 colgroups x 16 rowgroups; BM=64 rows; K staged in 2 phases.
__global__ __launch_bounds__(256) void k_gemm128(const float* __restrict__ X,
                                                 const float* __restrict__ W,
                                                 float* __restrict__ Y, int M) {
    __shared__ float wsm[64 * 128];  // 32 KB: W rows [kp*64, kp*64+64)
    __shared__ float xs[64 * 68];    // 17 KB: X tile [64 rows][64 k], pad 68
    int t = threadIdx.x;
    int row0 = blockIdx.x * 64;
    int cg = t & 15, rg = t >> 4;
    float acc[4][8];
#pragma unroll
    for (int a = 0; a < 4; ++a)
#pragma unroll
        for (int b = 0; b < 8; ++b) acc[a][b] = 0.f;

    for (int kp = 0; kp < 2; ++kp) {
        const float4* W4 = (const float4*)W;
        float4* wd = (float4*)wsm;
#pragma unroll
        for (int i = 0; i < 8; ++i) {  // 2048 float4 of W half
            int idx = t + i * 256;
            wd[idx] = W4[kp * 2048 + idx];
        }
        const float4* X4 = (const float4*)X;
#pragma unroll
        for (int i = 0; i < 4; ++i) {  // 1024 float4 of X tile
            int idx = t + i * 256;
            int r = idx >> 4, c4 = idx & 15;
            float4 v = {0.f, 0.f, 0.f, 0.f};
            if (row0 + r < M) v = X4[(size_t)(row0 + r) * 32 + kp * 16 + c4];
            float* dst = &xs[r * 68 + c4 * 4];
            dst[0] = v.x; dst[1] = v.y; dst[2] = v.z; dst[3] = v.w;
        }
        __syncthreads();
#pragma unroll 4
        for (int k = 0; k < 64; ++k) {
            float a0 = xs[(rg * 4 + 0) * 68 + k];
            float a1 = xs[(rg * 4 + 1) * 68 + k];
            float a2 = xs[(rg * 4 + 2) * 68 + k];
            float a3 = xs[(rg * 4 + 3) * 68 + k];
            const float* wr = &wsm[k * 128 + cg * 8];
            float4 w0 = *(const float4*)wr;
            float4 w1 = *(const float4*)(wr + 4);
            float wv[8] = {w0.x, w0.y, w0.z, w0.w, w1.x, w1.y, w1.z, w1.w};
#pragma unroll
            for (int b = 0; b < 8; ++b) {
                acc[0][b] = fmaf(a0, wv[b], acc[0][b]);
                acc[1][b] = fmaf(a1, wv[b], acc[1][b]);
                acc[2][b] = fmaf(a2, wv[b], acc[2][b]);
                acc[3][b] = fmaf(a3, wv[b], acc[3][b]);
            }
        }
        __syncthreads();
    }
#pragma unroll
    for (int a = 0; a < 4; ++a) {
        int r = row0 + rg * 4 + a;
        if (r < M) {
            float4* dst = (float4*)&Y[(size_t)r * 128 + cg * 8];
            float4 o0 = {acc[a][0], acc[a][1], acc[a][2], acc[a][3]};
            float4 o1 = {acc[a][4], acc[a][5], acc[a][6], acc[a][7]};
            dst[0] = o0;
            dst[1] = o1;
        }
    }
}

// ---- GEMM: Y[M][40] = X[M][128] @ W[128][40] ----
// block 320 = 5 waves; wave cg=t>>6 owns 8 cols, lane = row in 64-row tile.
__global__ __launch_bounds__(320) void k_gemm40(const float* __restrict__ X,
                                                const float* __restrict__ W,
                                                float* __restrict__ Y, int M) {
    __shared__ float wsm[128 * 40];  // 20 KB
    __shared__ float xs[64 * 133];   // 34 KB, pad 133 (coprime-ish banks)
    int t = threadIdx.x;
    int row0 = blockIdx.x * 64;
    for (int idx = t; idx < 128 * 40; idx += 320) wsm[idx] = W[idx];
    for (int idx = t; idx < 64 * 128; idx += 320) {
        int r = idx >> 7, c = idx & 127;
        xs[r * 133 + c] = (row0 + r < M) ? X[(size_t)(row0 + r) * 128 + c] : 0.f;
    }
    __syncthreads();
    int lane = t & 63, cg = t >> 6;  // cg 0..4
    float acc[8];
#pragma unroll
    for (int b = 0; b < 8; ++b) acc[b] = 0.f;
#pragma unroll 4
    for (int k = 0; k < 128; ++k) {
        float a = xs[lane * 133 + k];
        const float* wr = &wsm[k * 40 + cg * 8];
        float4 w0 = *(const float4*)wr;
        float4 w1 = *(const float4*)(wr + 4);
        acc[0] = fmaf(a, w0.x, acc[0]); acc[1] = fmaf(a, w0.y, acc[1]);
        acc[2] = fmaf(a, w0.z, acc[2]); acc[3] = fmaf(a, w0.w, acc[3]);
        acc[4] = fmaf(a, w1.x, acc[4]); acc[5] = fmaf(a, w1.y, acc[5]);
        acc[6] = fmaf(a, w1.z, acc[6]); acc[7] = fmaf(a, w1.w, acc[7]);
    }
    int r = row0 + lane;
    if (r < M) {
        float4* dst = (float4*)&Y[(size_t)r * 40 + cg * 8];
        float4 o0 = {acc[0], acc[1], acc[2], acc[3]};
        float4 o1 = {acc[4], acc[5], acc[6], acc[7]};
        dst[0] = o0;
        dst[1] = o1;
    }
}

// ---- aggregation, 128 features: one wave per node, lane owns float2 ----
__global__ __launch_bounds__(256) void k_agg128(const float* __restrict__ h,
                                                const float* __restrict__ dis,
                                                const int* __restrict__ ptr,
                                                const int* __restrict__ cnt,
                                                const int* __restrict__ esrc,
                                                const float* __restrict__ bias,
                                                float* __restrict__ out,
                                                int relu, int N) {
    int node = blockIdx.x * 4 + (threadIdx.x >> 6);
    if (node >= N) return;
    int lane = threadIdx.x & 63;
    float di = dis[node];
    const float2* hrow = (const float2*)(h + (size_t)node * 128);
    float2 self = hrow[lane];
    float w = di * di;
    float ax = self.x * w, ay = self.y * w;
    int start = ptr[node], c = cnt[node];
    for (int base = 0; base < c; base += 64) {
        int m = min(64, c - base);
        int e = 0;
        float dsl = 0.f;
        if (lane < m) {
            e = esrc[start + base + lane];
            dsl = dis[e];
        }
        int j = 0;
        for (; j + 2 <= m; j += 2) {  // 2 loads in flight
            int sA = __shfl(e, j), sB = __shfl(e, j + 1);
            float scA = __shfl(dsl, j) * di;
            float scB = __shfl(dsl, j + 1) * di;
            float2 vA = ((const float2*)(h + (size_t)sA * 128))[lane];
            float2 vB = ((const float2*)(h + (size_t)sB * 128))[lane];
            ax = fmaf(vA.x, scA, ax); ay = fmaf(vA.y, scA, ay);
            ax = fmaf(vB.x, scB, ax); ay = fmaf(vB.y, scB, ay);
        }
        if (j < m) {
            int sA = __shfl(e, j);
            float scA = __shfl(dsl, j) * di;
            float2 vA = ((const float2*)(h + (size_t)sA * 128))[lane];
            ax = fmaf(vA.x, scA, ax); ay = fmaf(vA.y, scA, ay);
        }
    }
    float2 b = ((const float2*)bias)[lane];
    ax += b.x; ay += b.y;
    if (relu) { ax = fmaxf(ax, 0.f); ay = fmaxf(ay, 0.f); }
    float2 o = {ax, ay};
    ((float2*)(out + (size_t)node * 128))[lane] = o;
}

// ---- aggregation, 40 features: one wave per node, lanes 0..39 ----
__global__ __launch_bounds__(256) void k_agg40(const float* __restrict__ h,
                                               const float* __restrict__ dis,
                                               const int* __restrict__ ptr,
                                               const int* __restrict__ cnt,
                                               const int* __restrict__ esrc,
                                               const float* __restrict__ bias,
                                               float* __restrict__ out, int N) {
    int node = blockIdx.x * 4 + (threadIdx.x >> 6);
    if (node >= N) return;
    int lane = threadIdx.x & 63;
    float di = dis[node];
    float acc = 0.f;
    if (lane < 40) acc = h[(size_t)node * 40 + lane] * di * di;
    int start = ptr[node], c = cnt[node];
    for (int base = 0; base < c; base += 64) {
        int m = min(64, c - base);
        int e = 0;
        float dsl = 0.f;
        if (lane < m) {
            e = esrc[start + base + lane];
            dsl = dis[e];
        }
        for (int j = 0; j < m; ++j) {
            int s = __shfl(e, j);
            float sc = __shfl(dsl, j) * di;
            if (lane < 40) acc = fmaf(h[(size_t)s * 40 + lane], sc, acc);
        }
    }
    if (lane < 40) out[(size_t)node * 40 + lane] = acc + bias[lane];
}

// ---- log_softmax over 40 classes, one wave per row ----
__global__ __launch_bounds__(256) void k_lsm(const float* __restrict__ in,
                                             float* __restrict__ out, int N) {
    int rowi = blockIdx.x * 4 + (threadIdx.x >> 6);
    if (rowi >= N) return;
    int lane = threadIdx.x & 63;
    float v = (lane < 40) ? in[(size_t)rowi * 40 + lane] : -INFINITY;
    float m = v;
#pragma unroll
    for (int o = 32; o; o >>= 1) m = fmaxf(m, __shfl_xor(m, o));
    float ex = (lane < 40) ? expf(v - m) : 0.f;
    float s = ex;
#pragma unroll
    for (int o = 32; o; o >>= 1) s += __shfl_xor(s, o);
    if (lane < 40) out[(size_t)rowi * 40 + lane] = v - m - logf(s);
}

extern "C" void kernel_launch(void* const* d_in, const int* in_sizes, int n_in,
                              void* d_out, int out_size, void* d_ws, size_t ws_size,
                              hipStream_t stream) {
    const float* x  = (const float*)d_in[0];
    const int*   ei = (const int*)d_in[1];
    const float* W1 = (const float*)d_in[2];
    const float* b1 = (const float*)d_in[3];
    const float* W2 = (const float*)d_in[4];
    const float* b2 = (const float*)d_in[5];
    const float* W3 = (const float*)d_in[6];
    const float* b3 = (const float*)d_in[7];
    int N = in_sizes[0] / 128;
    int E = in_sizes[1] / 2;
    const int* row = ei;
    const int* col = ei + E;

    char* ws = (char*)d_ws;
    size_t off = 0;
    auto alloc = [&](size_t bytes) {
        void* p = ws + off;
        off += (bytes + 255) & ~(size_t)255;
        return p;
    };
    float* hA   = (float*)alloc((size_t)N * 128 * 4);
    float* hB   = (float*)alloc((size_t)N * 128 * 4);
    int*   esrc = (int*)alloc((size_t)E * 4);
    int*   cptr = (int*)alloc((size_t)N * 4);
    int*   cnt  = (int*)alloc((size_t)N * 4);
    int*   cur  = (int*)alloc((size_t)N * 4);
    float* dis  = (float*)alloc((size_t)N * 4);
    float* t3   = hA;                      // reuse hA after agg2 consumed it
    float* t3b  = hA + (size_t)N * 40;

    hipMemsetAsync(cnt, 0, (size_t)N * 4, stream);
    k_count<<<(E + 255) / 256, 256, 0, stream>>>(col, E, cnt);
    k_scan<<<1, 1024, 0, stream>>>(cnt, cptr, cur, dis, N);
    k_fill<<<(E + 255) / 256, 256, 0, stream>>>(row, col, E, cur, esrc);

    int gb = (N + 63) / 64;
    int ab = (N + 3) / 4;
    k_gemm128<<<gb, 256, 0, stream>>>(x, W1, hA, N);
    k_agg128<<<ab, 256, 0, stream>>>(hA, dis, cptr, cnt, esrc, b1, hB, 1, N);
    k_gemm128<<<gb, 256, 0, stream>>>(hB, W2, hA, N);
    k_agg128<<<ab, 256, 0, stream>>>(hA, dis, cptr, cnt, esrc, b2, hB, 1, N);
    k_gemm40<<<gb, 320, 0, stream>>>(hB, W3, t3, N);
    k_agg40<<<ab, 256, 0, stream>>>(t3, dis, cptr, cnt, esrc, b3, t3b, N);
    k_lsm<<<ab, 256, 0, stream>>>(t3b, (float*)d_out, N);
}

// Round 3
// 834.723 us; speedup vs baseline: 1.3110x; 1.3110x over previous
//
#include <hip/hip_runtime.h>
#include <hip/hip_bf16.h>
#include <math.h>

// ---------------------------------------------------------------------------
// 3-layer GCN: per layer  h' = Dis (A+I) Dis (h W) + b   (Dis = D^{-1/2})
// Pipeline: count deg -> 3-kernel parallel scan (ptr, cursor, dis) ->
//           fill CSR(by dst) -> gemm -> aggregate(+bias,+relu) x3 -> lsm
// ---------------------------------------------------------------------------

__global__ void k_count(const int* __restrict__ col, int E, int* __restrict__ cnt) {
    int i = blockIdx.x * blockDim.x + threadIdx.x;
    if (i < E) atomicAdd(&cnt[col[i]], 1);
}

// ---- parallel scan, stage 1: per-block (1024 elems) sums ----
__global__ __launch_bounds__(256) void k_bsum(const int* __restrict__ cnt, int N,
                                              int* __restrict__ bsum) {
    int t = threadIdx.x;
    int base = blockIdx.x * 1024 + t * 4;
    int s = 0;
    if (base + 3 < N) {
        int4 v = *(const int4*)(cnt + base);
        s = v.x + v.y + v.z + v.w;
    } else {
        for (int j = 0; j < 4; ++j)
            if (base + j < N) s += cnt[base + j];
    }
#pragma unroll
    for (int off = 32; off; off >>= 1) s += __shfl_xor(s, off);
    __shared__ int ws[4];
    int lane = t & 63, w = t >> 6;
    if (lane == 0) ws[w] = s;
    __syncthreads();
    if (t == 0) bsum[blockIdx.x] = ws[0] + ws[1] + ws[2] + ws[3];
}

// ---- stage 2: exclusive scan of block sums (B <= 128), one tiny block ----
__global__ __launch_bounds__(128) void k_sbsum(int* __restrict__ bsum, int B) {
    __shared__ int sm[128];
    int t = threadIdx.x;
    int v = (t < B) ? bsum[t] : 0;
    sm[t] = v;
    __syncthreads();
    for (int off = 1; off < 128; off <<= 1) {
        int u = (t >= off) ? sm[t - off] : 0;
        __syncthreads();
        sm[t] += u;
        __syncthreads();
    }
    if (t < B) bsum[t] = sm[t] - v;  // exclusive prefix
}

// ---- stage 3: per-block exclusive scan + write ptr/cur/dis ----
__global__ __launch_bounds__(256) void k_wptr(const int* __restrict__ cnt,
                                              const int* __restrict__ bsum, int N,
                                              int* __restrict__ ptr,
                                              int* __restrict__ cur,
                                              float* __restrict__ dis) {
    int t = threadIdx.x;
    int base = blockIdx.x * 1024 + t * 4;
    int c[4];
    int s = 0;
    if (base + 3 < N) {
        int4 v = *(const int4*)(cnt + base);
        c[0] = v.x; c[1] = v.y; c[2] = v.z; c[3] = v.w;
        s = v.x + v.y + v.z + v.w;
    } else {
#pragma unroll
        for (int j = 0; j < 4; ++j) {
            c[j] = (base + j < N) ? cnt[base + j] : 0;
            s += c[j];
        }
    }
    int lane = t & 63, w = t >> 6;
    int incl = s;
#pragma unroll
    for (int off = 1; off < 64; off <<= 1) {
        int u = __shfl_up(incl, off);
        if (lane >= off) incl += u;
    }
    __shared__ int wsum[4];
    if (lane == 63) wsum[w] = incl;
    __syncthreads();
    int run = bsum[blockIdx.x] + (incl - s);
    for (int j = 0; j < w; ++j) run += wsum[j];
#pragma unroll
    for (int j = 0; j < 4; ++j) {
        int i = base + j;
        if (i < N) {
            ptr[i] = run;
            cur[i] = run;
            dis[i] = rsqrtf((float)(c[j] + 1));  // +1 self-loop
            run += c[j];
        }
    }
}

__global__ void k_fill(const int* __restrict__ row, const int* __restrict__ col,
                       int E, int* __restrict__ cur, int* __restrict__ esrc) {
    int i = blockIdx.x * blockDim.x + threadIdx.x;
    if (i < E) {
        int p = atomicAdd(&cur[col[i]], 1);
        esrc[p] = row[i];
    }
}

// ---- GEMM: Y[M][128] = X[M][128] @ W[128][128], no bias (added post-agg) ----
__global__ __launch_bounds__(256) void k_gemm128(const float* __restrict__ X,
                                                 const float* __restrict__ W,
                                                 float* __restrict__ Y, int M) {
    __shared__ float wsm[64 * 128];  // 32 KB: W rows [kp*64, kp*64+64)
    __shared__ float xs[64 * 68];    // 17 KB: X tile [64 rows][64 k], pad 68
    int t = threadIdx.x;
    int row0 = blockIdx.x * 64;
    int cg = t & 15, rg = t >> 4;
    float acc[4][8];
#pragma unroll
    for (int a = 0; a < 4; ++a)
#pragma unroll
        for (int b = 0; b < 8; ++b) acc[a][b] = 0.f;

    for (int kp = 0; kp < 2; ++kp) {
        const float4* W4 = (const float4*)W;
        float4* wd = (float4*)wsm;
#pragma unroll
        for (int i = 0; i < 8; ++i) {
            int idx = t + i * 256;
            wd[idx] = W4[kp * 2048 + idx];
        }
        const float4* X4 = (const float4*)X;
#pragma unroll
        for (int i = 0; i < 4; ++i) {
            int idx = t + i * 256;
            int r = idx >> 4, c4 = idx & 15;
            float4 v = {0.f, 0.f, 0.f, 0.f};
            if (row0 + r < M) v = X4[(size_t)(row0 + r) * 32 + kp * 16 + c4];
            float* dst = &xs[r * 68 + c4 * 4];
            dst[0] = v.x; dst[1] = v.y; dst[2] = v.z; dst[3] = v.w;
        }
        __syncthreads();
#pragma unroll 4
        for (int k = 0; k < 64; ++k) {
            float a0 = xs[(rg * 4 + 0) * 68 + k];
            float a1 = xs[(rg * 4 + 1) * 68 + k];
            float a2 = xs[(rg * 4 + 2) * 68 + k];
            float a3 = xs[(rg * 4 + 3) * 68 + k];
            const float* wr = &wsm[k * 128 + cg * 8];
            float4 w0 = *(const float4*)wr;
            float4 w1 = *(const float4*)(wr + 4);
            float wv[8] = {w0.x, w0.y, w0.z, w0.w, w1.x, w1.y, w1.z, w1.w};
#pragma unroll
            for (int b = 0; b < 8; ++b) {
                acc[0][b] = fmaf(a0, wv[b], acc[0][b]);
                acc[1][b] = fmaf(a1, wv[b], acc[1][b]);
                acc[2][b] = fmaf(a2, wv[b], acc[2][b]);
                acc[3][b] = fmaf(a3, wv[b], acc[3][b]);
            }
        }
        __syncthreads();
    }
#pragma unroll
    for (int a = 0; a < 4; ++a) {
        int r = row0 + rg * 4 + a;
        if (r < M) {
            float4* dst = (float4*)&Y[(size_t)r * 128 + cg * 8];
            float4 o0 = {acc[a][0], acc[a][1], acc[a][2], acc[a][3]};
            float4 o1 = {acc[a][4], acc[a][5], acc[a][6], acc[a][7]};
            dst[0] = o0;
            dst[1] = o1;
        }
    }
}

// ---- GEMM: Y[M][40] = X[M][128] @ W[128][40] ----
__global__ __launch_bounds__(320) void k_gemm40(const float* __restrict__ X,
                                                const float* __restrict__ W,
                                                float* __restrict__ Y, int M) {
    __shared__ float wsm[128 * 40];  // 20 KB
    __shared__ float xs[64 * 133];   // 34 KB
    int t = threadIdx.x;
    int row0 = blockIdx.x * 64;
    for (int idx = t; idx < 128 * 40; idx += 320) wsm[idx] = W[idx];
    for (int idx = t; idx < 64 * 128; idx += 320) {
        int r = idx >> 7, c = idx & 127;
        xs[r * 133 + c] = (row0 + r < M) ? X[(size_t)(row0 + r) * 128 + c] : 0.f;
    }
    __syncthreads();
    int lane = t & 63, cg = t >> 6;  // cg 0..4
    float acc[8];
#pragma unroll
    for (int b = 0; b < 8; ++b) acc[b] = 0.f;
#pragma unroll 4
    for (int k = 0; k < 128; ++k) {
        float a = xs[lane * 133 + k];
        const float* wr = &wsm[k * 40 + cg * 8];
        float4 w0 = *(const float4*)wr;
        float4 w1 = *(const float4*)(wr + 4);
        acc[0] = fmaf(a, w0.x, acc[0]); acc[1] = fmaf(a, w0.y, acc[1]);
        acc[2] = fmaf(a, w0.z, acc[2]); acc[3] = fmaf(a, w0.w, acc[3]);
        acc[4] = fmaf(a, w1.x, acc[4]); acc[5] = fmaf(a, w1.y, acc[5]);
        acc[6] = fmaf(a, w1.z, acc[6]); acc[7] = fmaf(a, w1.w, acc[7]);
    }
    int r = row0 + lane;
    if (r < M) {
        float4* dst = (float4*)&Y[(size_t)r * 40 + cg * 8];
        float4 o0 = {acc[0], acc[1], acc[2], acc[3]};
        float4 o1 = {acc[4], acc[5], acc[6], acc[7]};
        dst[0] = o0;
        dst[1] = o1;
    }
}

// ---- aggregation, 128 features: one wave per node, lane owns float2 ----
__global__ __launch_bounds__(256) void k_agg128(const float* __restrict__ h,
                                                const float* __restrict__ dis,
                                                const int* __restrict__ ptr,
                                                const int* __restrict__ cnt,
                                                const int* __restrict__ esrc,
                                                const float* __restrict__ bias,
                                                float* __restrict__ out,
                                                int relu, int N) {
    int node = blockIdx.x * 4 + (threadIdx.x >> 6);
    if (node >= N) return;
    int lane = threadIdx.x & 63;
    float di = dis[node];
    const float2* hrow = (const float2*)(h + (size_t)node * 128);
    float2 self = hrow[lane];
    float w = di * di;
    float ax = self.x * w, ay = self.y * w;
    int start = ptr[node], c = cnt[node];
    for (int base = 0; base < c; base += 64) {
        int m = min(64, c - base);
        int e = 0;
        float dsl = 0.f;
        if (lane < m) {
            e = esrc[start + base + lane];
            dsl = dis[e];
        }
        int j = 0;
        for (; j + 2 <= m; j += 2) {
            int sA = __shfl(e, j), sB = __shfl(e, j + 1);
            float scA = __shfl(dsl, j) * di;
            float scB = __shfl(dsl, j + 1) * di;
            float2 vA = ((const float2*)(h + (size_t)sA * 128))[lane];
            float2 vB = ((const float2*)(h + (size_t)sB * 128))[lane];
            ax = fmaf(vA.x, scA, ax); ay = fmaf(vA.y, scA, ay);
            ax = fmaf(vB.x, scB, ax); ay = fmaf(vB.y, scB, ay);
        }
        if (j < m) {
            int sA = __shfl(e, j);
            float scA = __shfl(dsl, j) * di;
            float2 vA = ((const float2*)(h + (size_t)sA * 128))[lane];
            ax = fmaf(vA.x, scA, ax); ay = fmaf(vA.y, scA, ay);
        }
    }
    float2 b = ((const float2*)bias)[lane];
    ax += b.x; ay += b.y;
    if (relu) { ax = fmaxf(ax, 0.f); ay = fmaxf(ay, 0.f); }
    float2 o = {ax, ay};
    ((float2*)(out + (size_t)node * 128))[lane] = o;
}

// ---- aggregation, 40 features: one wave per node, lanes 0..39 ----
__global__ __launch_bounds__(256) void k_agg40(const float* __restrict__ h,
                                               const float* __restrict__ dis,
                                               const int* __restrict__ ptr,
                                               const int* __restrict__ cnt,
                                               const int* __restrict__ esrc,
                                               const float* __restrict__ bias,
                                               float* __restrict__ out, int N) {
    int node = blockIdx.x * 4 + (threadIdx.x >> 6);
    if (node >= N) return;
    int lane = threadIdx.x & 63;
    float di = dis[node];
    float acc = 0.f;
    if (lane < 40) acc = h[(size_t)node * 40 + lane] * di * di;
    int start = ptr[node], c = cnt[node];
    for (int base = 0; base < c; base += 64) {
        int m = min(64, c - base);
        int e = 0;
        float dsl = 0.f;
        if (lane < m) {
            e = esrc[start + base + lane];
            dsl = dis[e];
        }
        for (int j = 0; j < m; ++j) {
            int s = __shfl(e, j);
            float sc = __shfl(dsl, j) * di;
            if (lane < 40) acc = fmaf(h[(size_t)s * 40 + lane], sc, acc);
        }
    }
    if (lane < 40) out[(size_t)node * 40 + lane] = acc + bias[lane];
}

// ---- log_softmax over 40 classes, one wave per row ----
__global__ __launch_bounds__(256) void k_lsm(const float* __restrict__ in,
                                             float* __restrict__ out, int N) {
    int rowi = blockIdx.x * 4 + (threadIdx.x >> 6);
    if (rowi >= N) return;
    int lane = threadIdx.x & 63;
    float v = (lane < 40) ? in[(size_t)rowi * 40 + lane] : -INFINITY;
    float m = v;
#pragma unroll
    for (int o = 32; o; o >>= 1) m = fmaxf(m, __shfl_xor(m, o));
    float ex = (lane < 40) ? expf(v - m) : 0.f;
    float s = ex;
#pragma unroll
    for (int o = 32; o; o >>= 1) s += __shfl_xor(s, o);
    if (lane < 40) out[(size_t)rowi * 40 + lane] = v - m - logf(s);
}

extern "C" void kernel_launch(void* const* d_in, const int* in_sizes, int n_in,
                              void* d_out, int out_size, void* d_ws, size_t ws_size,
                              hipStream_t stream) {
    const float* x  = (const float*)d_in[0];
    const int*   ei = (const int*)d_in[1];
    const float* W1 = (const float*)d_in[2];
    const float* b1 = (const float*)d_in[3];
    const float* W2 = (const float*)d_in[4];
    const float* b2 = (const float*)d_in[5];
    const float* W3 = (const float*)d_in[6];
    const float* b3 = (const float*)d_in[7];
    int N = in_sizes[0] / 128;
    int E = in_sizes[1] / 2;
    const int* row = ei;
    const int* col = ei + E;

    char* ws = (char*)d_ws;
    size_t off = 0;
    auto alloc = [&](size_t bytes) {
        void* p = ws + off;
        off += (bytes + 255) & ~(size_t)255;
        return p;
    };
    float* hA   = (float*)alloc((size_t)N * 128 * 4);
    float* hB   = (float*)alloc((size_t)N * 128 * 4);
    int*   esrc = (int*)alloc((size_t)E * 4);
    int*   cptr = (int*)alloc((size_t)N * 4);
    int*   cnt  = (int*)alloc((size_t)N * 4);
    int*   cur  = (int*)alloc((size_t)N * 4);
    float* dis  = (float*)alloc((size_t)N * 4);
    int*   bsum = (int*)alloc(256 * 4);
    float* t3   = hA;                      // reuse hA after agg2 consumed it
    float* t3b  = hA + (size_t)N * 40;

    hipMemsetAsync(cnt, 0, (size_t)N * 4, stream);
    k_count<<<(E + 255) / 256, 256, 0, stream>>>(col, E, cnt);
    int B = (N + 1023) / 1024;  // 98 for N=100000 (must be <=128)
    k_bsum<<<B, 256, 0, stream>>>(cnt, N, bsum);
    k_sbsum<<<1, 128, 0, stream>>>(bsum, B);
    k_wptr<<<B, 256, 0, stream>>>(cnt, bsum, N, cptr, cur, dis);
    k_fill<<<(E + 255) / 256, 256, 0, stream>>>(row, col, E, cur, esrc);

    int gb = (N + 63) / 64;
    int ab = (N + 3) / 4;
    k_gemm128<<<gb, 256, 0, stream>>>(x, W1, hA, N);
    k_agg128<<<ab, 256, 0, stream>>>(hA, dis, cptr, cnt, esrc, b1, hB, 1, N);
    k_gemm128<<<gb, 256, 0, stream>>>(hB, W2, hA, N);
    k_agg128<<<ab, 256, 0, stream>>>(hA, dis, cptr, cnt, esrc, b2, hB, 1, N);
    k_gemm40<<<gb, 320, 0, stream>>>(hB, W3, t3, N);
    k_agg40<<<ab, 256, 0, stream>>>(t3, dis, cptr, cnt, esrc, b3, t3b, N);
    k_lsm<<<ab, 256, 0, stream>>>(t3b, (float*)d_out, N);
}